// Round 2
// baseline (292.277 us; speedup 1.0000x reference)
//
#include <hip/hip_runtime.h>
#include <math.h>

// FeatureWeightNet fused kernel v2 (MI355X / gfx950)
// B=2, C=64, H=512, W=640, NB=9, G=8.
// Thread = 4 consecutive pixels; block = 64x16 tile (16 thr-x * 16 thr-y).
// All tap column shifts are even -> 3 aligned float4 loads per stencil row
// cover wide(-4,0,4) AND narrow(-2,0,2) taps for 4 pixels.
// XCD-bijective block swizzle (640 blocks = 8 XCDs * 80) for vertical halo
// reuse in per-XCD L2.

typedef float f4 __attribute__((ext_vector_type(4)));

#define EPSV 1e-5f

template<bool INTERIOR>
__device__ __forceinline__ void accum_channels(
    const float* __restrict__ Fb, float* __restrict__ ab, int HW,
    const int* vrow, const int* rowoff, const int* colidx,
    const f4* ob, const f4* os, f4* xs)
{
    #pragma unroll 2
    for (int c = 0; c < 64; ++c) {
        const float* cb = Fb + (size_t)c * HW;   // uniform base per channel
        f4 acc = {0.f, 0.f, 0.f, 0.f};
        #pragma unroll
        for (int r = 0; r < 5; ++r) {            // rows dy = {-4,-2,0,2,4}
            float rb[12];                        // cols w-4 .. w+7
            if (INTERIOR) {
                f4 a0 = *(const f4*)(cb + vrow[r]);
                f4 a1 = *(const f4*)(cb + vrow[r] + 4);
                f4 a2 = *(const f4*)(cb + vrow[r] + 8);
                #pragma unroll
                for (int j = 0; j < 4; ++j) {
                    rb[j] = a0[j]; rb[4 + j] = a1[j]; rb[8 + j] = a2[j];
                }
            } else {
                #pragma unroll
                for (int j = 0; j < 12; ++j) rb[j] = cb[rowoff[r] + colidx[j]];
            }
            if ((r & 1) == 0) {                  // wide taps, sy = r/2
                const int sy = r >> 1;
                #pragma unroll
                for (int sx = 0; sx < 3; ++sx)
                    #pragma unroll
                    for (int p = 0; p < 4; ++p)
                        acc[p] += ob[sy * 3 + sx][p] * rb[4 * sx + p];
            }
            if (r >= 1 && r <= 3) {              // narrow taps, sy = r-1
                const int sy = r - 1;
                #pragma unroll
                for (int sx = 0; sx < 3; ++sx)
                    #pragma unroll
                    for (int p = 0; p < 4; ++p)
                        acc[p] += os[sy * 3 + sx][p] * rb[2 + 2 * sx + p];
            }
        }
        __builtin_nontemporal_store(acc, (f4*)(ab + (size_t)c * HW));
        xs[c >> 3] += acc;
    }
}

__global__ __launch_bounds__(256) void fwn_kernel(
    const float* __restrict__ F,    // [B,64,H,W]
    const float* __restrict__ off,  // [B,18,H,W]
    const float* __restrict__ w0, const float* __restrict__ b0,
    const float* __restrict__ g0, const float* __restrict__ beta0,
    const float* __restrict__ m0, const float* __restrict__ v0,
    const float* __restrict__ w1, const float* __restrict__ b1,
    const float* __restrict__ g1, const float* __restrict__ beta1,
    const float* __restrict__ m1, const float* __restrict__ v1,
    const float* __restrict__ ws, const float* __restrict__ bs,
    float* __restrict__ sig,        // [B,H,W]
    float* __restrict__ accp,       // [B,64,H,W]
    int H, int W)
{
    const int HW = H * W;
    const int C = 64;

    // XCD-bijective swizzle: 640 blocks = 8 * 80; XCD k gets a contiguous
    // logical range; logical order is y-fastest (vertical L2 reuse).
    const int f = blockIdx.x;
    const int l = (f & 7) * 80 + (f >> 3);
    const int b  = l / 320;
    const int r_ = l % 320;
    const int bx = r_ >> 5;    // 0..9  (x tile, 64 px)
    const int by = r_ & 31;    // 0..31 (y tile, 16 px)

    const int tid = threadIdx.x;
    const int w = bx * 64 + (tid & 15) * 4;   // first of 4 pixels
    const int h = by * 16 + (tid >> 4);

    // reflected rows for dy = {-4,-2,0,2,4}
    int rowoff[5];
    #pragma unroll
    for (int k = 0; k < 5; ++k) {
        int hh = h + 2 * k - 4;
        if (hh < 0) hh = -hh;
        if (hh >= H) hh = 2 * H - 2 - hh;
        rowoff[k] = hh * W;
    }
    int vrow[5];
    #pragma unroll
    for (int k = 0; k < 5; ++k) vrow[k] = rowoff[k] + w - 4;

    // reflected cols (border path only)
    int colidx[12];
    #pragma unroll
    for (int j = 0; j < 12; ++j) {
        int x = w - 4 + j;
        if (x < 0) x = -x;
        if (x >= W) x = 2 * W - 2 - x;
        colidx[j] = x;
    }

    // per-pixel tap weights (float4 over the 4 pixels), pre-scaled by 0.5
    const float* op = off + (size_t)b * 18 * HW + h * W + w;
    f4 ob[9], os[9];
    #pragma unroll
    for (int s = 0; s < 9; ++s) {
        ob[s] = 0.5f * __builtin_nontemporal_load((const f4*)(op + (size_t)s * HW));
        os[s] = 0.5f * __builtin_nontemporal_load((const f4*)(op + (size_t)(s + 9) * HW));
    }

    const float* Fb = F + (size_t)b * C * HW;
    float* ab = accp + (size_t)b * C * HW + h * W + w;

    f4 xs[8];
    #pragma unroll
    for (int g = 0; g < 8; ++g) xs[g] = (f4){0.f, 0.f, 0.f, 0.f};

    const bool interior = (bx >= 1) && (bx <= 8);
    if (interior)
        accum_channels<true >(Fb, ab, HW, vrow, rowoff, colidx, ob, os, xs);
    else
        accum_channels<false>(Fb, ab, HW, vrow, rowoff, colidx, ob, os, xs);

    // ---- fused BN+MLP head per pixel ----
    f4 sv;
    #pragma unroll
    for (int p = 0; p < 4; ++p) {
        float x[8];
        #pragma unroll
        for (int g = 0; g < 8; ++g) x[g] = xs[g][p] * 0.125f;
        float y0[16];
        #pragma unroll
        for (int o = 0; o < 16; ++o) {
            const float s0 = g0[o] * rsqrtf(v0[o] + EPSV);
            float z = 0.f;
            #pragma unroll
            for (int i = 0; i < 8; ++i) z += w0[o * 8 + i] * x[i];
            z = z * s0 + (b0[o] - m0[o]) * s0 + beta0[o];
            y0[o] = fmaxf(z, 0.f);
        }
        float y1[8];
        #pragma unroll
        for (int o = 0; o < 8; ++o) {
            const float s1 = g1[o] * rsqrtf(v1[o] + EPSV);
            float z = 0.f;
            #pragma unroll
            for (int i = 0; i < 16; ++i) z += w1[o * 16 + i] * y0[i];
            z = z * s1 + (b1[o] - m1[o]) * s1 + beta1[o];
            y1[o] = fmaxf(z, 0.f);
        }
        float sm = bs[0];
        #pragma unroll
        for (int i = 0; i < 8; ++i) sm += ws[i] * y1[i];
        sv[p] = 1.f / (1.f + __expf(-sm));
    }
    *(f4*)(sig + (size_t)b * HW + h * W + w) = sv;
}

extern "C" void kernel_launch(void* const* d_in, const int* in_sizes, int n_in,
                              void* d_out, int out_size, void* d_ws, size_t ws_size,
                              hipStream_t stream) {
    const float* F    = (const float*)d_in[0];
    const float* off  = (const float*)d_in[1];
    const float* w0   = (const float*)d_in[2];
    const float* b0   = (const float*)d_in[3];
    const float* g0   = (const float*)d_in[4];
    const float* bt0  = (const float*)d_in[5];
    const float* m0   = (const float*)d_in[6];
    const float* v0   = (const float*)d_in[7];
    const float* w1   = (const float*)d_in[8];
    const float* b1   = (const float*)d_in[9];
    const float* g1   = (const float*)d_in[10];
    const float* bt1  = (const float*)d_in[11];
    const float* m1   = (const float*)d_in[12];
    const float* v1   = (const float*)d_in[13];
    const float* ws   = (const float*)d_in[14];
    const float* bs   = (const float*)d_in[15];

    const int B = 2, H = 512, W = 640;
    float* sig  = (float*)d_out;                  // [B,H,W]
    float* accp = sig + (size_t)B * H * W;        // [B,C,H,W]

    // grid: 10 x-tiles * 32 y-tiles * 2 batches = 640 blocks (8 XCDs * 80)
    fwn_kernel<<<dim3(640), dim3(256), 0, stream>>>(
        F, off, w0, b0, g0, bt0, m0, v0,
        w1, b1, g1, bt1, m1, v1, ws, bs,
        sig, accp, H, W);
}